// Round 2
// baseline (6432.669 us; speedup 1.0000x reference)
//
#include <hip/hip_runtime.h>

#define SEQ    1024
#define HID    512
#define OUTD   10
#define RPB    16            // batch rows per block
#define NBLK   32            // 512 / RPB
#define CPW    32            // output columns per wave
#define NT     2             // 16-col MFMA tiles per wave

typedef float f32x4  __attribute__((ext_vector_type(4)));
typedef short bf16x8 __attribute__((ext_vector_type(8)));

__device__ __forceinline__ unsigned short f2bf(float f) {
    unsigned u = __builtin_bit_cast(unsigned, f);
    u += 0x7fffu + ((u >> 16) & 1u);          // round-to-nearest-even
    return (unsigned short)(u >> 16);
}

// W_hh fp32 -> bf16 (RTN) into workspace; must rerun every launch (ws re-poisoned).
__global__ void w_prep(const float* __restrict__ W, unsigned short* __restrict__ Wbf) {
    int i = blockIdx.x * blockDim.x + threadIdx.x;
    if (i < HID * HID) Wbf[i] = f2bf(W[i]);
}

// One block (1024 thr = 16 waves) owns 16 batch rows for all 1024 steps.
// Wave w holds W_hh columns [32w, 32w+32) as MFMA B-fragments in 128 VGPRs.
// MFMA 16x16x32 bf16 layouts: A lane l -> row=l&15, k=(l>>4)*8+j (16B contig)
//                             B lane l -> col=l&15, k=(l>>4)*8+j (16B contig)
//                             D lane l -> col=l&15, row=(l>>4)*4+r  [m89]
// h lives in LDS (double-buffered, XOR-swizzled byte^((row&7)<<4) to kill the
// stride-1024B bank conflict on ds_read_b128). One barrier per step.
__global__ __launch_bounds__(1024) void rnn_kernel(
    const float* __restrict__ x,     // [512][1024]
    const float* __restrict__ W_hx,  // [512][1]
    const float* __restrict__ b_hx,  // [512]
    const float* __restrict__ b_hh,  // [512]
    const unsigned short* __restrict__ Wbf, // bf16 [512][512] row-major
    const float* __restrict__ W_oh,  // [10][512]
    const float* __restrict__ b_oh,  // [10]
    float* __restrict__ out)         // [512][10]
{
    __shared__ unsigned short hbuf[2][RPB][HID];  // 32 KB
    __shared__ float obuf[RPB][OUTD];

    const int tid  = threadIdx.x;
    const int lane = tid & 63;
    const int wv   = tid >> 6;        // 0..15
    const int row0 = blockIdx.x * RPB;
    const int crow = lane & 15;       // A-row / B-col / D-col
    const int kb   = lane >> 4;       // k-subblock
    const int dr0  = kb * 4;          // D row base

    // ---- W fragments resident in registers (loaded once) ----
    bf16x8 wfr[NT][16];
#pragma unroll
    for (int nt = 0; nt < NT; ++nt) {
        const int col = wv * CPW + nt * 16 + crow;
#pragma unroll
        for (int kt = 0; kt < 16; ++kt)
            wfr[nt][kt] = *(const bf16x8*)(Wbf + (size_t)col * HID + kt * 32 + kb * 8);
    }
    float whx[NT], bc[NT];
#pragma unroll
    for (int nt = 0; nt < NT; ++nt) {
        const int col = wv * CPW + nt * 16 + crow;
        whx[nt] = W_hx[col];
        bc[nt]  = b_hx[col] + b_hh[col];
    }

    for (int i = tid; i < 2 * RPB * HID; i += 1024)
        ((unsigned short*)hbuf)[i] = 0;          // h0 = 0

    const int abase = crow * (HID * 2) + kb * 16;
    const int amask = (crow & 7) << 4;

    __syncthreads();

    for (int t = 0; t < SEQ; ++t) {
        const char* hr = (const char*)hbuf[t & 1];
        char*       hw = (char*)hbuf[(t + 1) & 1];

        // x values consumed in the epilogue; latency hides under the GEMM
        float xv[4];
#pragma unroll
        for (int r = 0; r < 4; ++r)
            xv[r] = x[(size_t)(row0 + dr0 + r) * SEQ + t];

        f32x4 acc[NT];
#pragma unroll
        for (int nt = 0; nt < NT; ++nt) acc[nt] = (f32x4){0.f, 0.f, 0.f, 0.f};

        bf16x8 afr[2];
        afr[0] = *(const bf16x8*)(hr + (abase ^ amask));
#pragma unroll
        for (int kt = 0; kt < 16; ++kt) {
            if (kt + 1 < 16)                      // depth-1 LDS prefetch
                afr[(kt + 1) & 1] =
                    *(const bf16x8*)(hr + ((abase + (kt + 1) * 64) ^ amask));
#pragma unroll
            for (int nt = 0; nt < NT; ++nt)
                acc[nt] = __builtin_amdgcn_mfma_f32_16x16x32_bf16(
                    afr[kt & 1], wfr[nt][kt], acc[nt], 0, 0, 0);
        }

        // epilogue: pre-activation + tanh + bf16 store (swizzled)
#pragma unroll
        for (int nt = 0; nt < NT; ++nt) {
            const int col = wv * CPW + nt * 16 + crow;
#pragma unroll
            for (int r = 0; r < 4; ++r) {
                const int row = dr0 + r;
                float pre = acc[nt][r] + xv[r] * whx[nt] + bc[nt];
                // tanh(p) = 1 - 2/(exp(2p)+1); exp overflow/underflow saturate correctly
                float e = __expf(2.0f * pre);
                float h = 1.0f - 2.0f / (e + 1.0f);
                int ad = (row * (HID * 2) + col * 2) ^ ((row & 7) << 4);
                *(unsigned short*)(hw + ad) = f2bf(h);
            }
        }
        __syncthreads();   // writes to hw visible before next step reads it
    }

    // ---- output projection + softmax (once; final h is in hbuf[0]) ----
    if (tid < RPB * OUTD) {
        const int bl = tid / OUTD, j = tid % OUTD;
        const char* hr = (const char*)hbuf[SEQ & 1];
        float s = b_oh[j];
        const float* wrow = W_oh + j * HID;
        for (int k = 0; k < HID; ++k) {
            int ad = (bl * (HID * 2) + k * 2) ^ ((bl & 7) << 4);
            unsigned short hu = *(const unsigned short*)(hr + ad);
            s += __builtin_bit_cast(float, ((unsigned)hu) << 16) * wrow[k];
        }
        obuf[bl][j] = s;
    }
    __syncthreads();
    if (tid < RPB) {
        float m = -1e30f;
#pragma unroll
        for (int j = 0; j < OUTD; ++j) m = fmaxf(m, obuf[tid][j]);
        float e[OUTD], ss = 0.f;
#pragma unroll
        for (int j = 0; j < OUTD; ++j) { e[j] = __expf(obuf[tid][j] - m); ss += e[j]; }
        float inv = 1.0f / ss;
#pragma unroll
        for (int j = 0; j < OUTD; ++j)
            out[(size_t)(row0 + tid) * OUTD + j] = e[j] * inv;
    }
}

extern "C" void kernel_launch(void* const* d_in, const int* in_sizes, int n_in,
                              void* d_out, int out_size, void* d_ws, size_t ws_size,
                              hipStream_t stream) {
    (void)in_sizes; (void)n_in; (void)out_size; (void)ws_size;
    const float* x    = (const float*)d_in[0];
    const float* W_hx = (const float*)d_in[1];
    const float* b_hx = (const float*)d_in[2];
    const float* W_hh = (const float*)d_in[3];
    const float* b_hh = (const float*)d_in[4];
    const float* W_oh = (const float*)d_in[5];
    const float* b_oh = (const float*)d_in[6];
    float* out = (float*)d_out;
    unsigned short* Wbf = (unsigned short*)d_ws;   // 512 KB scratch

    w_prep<<<dim3((HID * HID + 255) / 256), dim3(256), 0, stream>>>(W_hh, Wbf);
    rnn_kernel<<<dim3(NBLK), dim3(1024), 0, stream>>>(x, W_hx, b_hx, b_hh, Wbf,
                                                      W_oh, b_oh, out);
}